// Round 3
// baseline (643.851 us; speedup 1.0000x reference)
//
#include <hip/hip_runtime.h>
#include <cstdint>
#include <cstddef>

typedef float  f32x4  __attribute__((ext_vector_type(4)));
typedef float  f32x16 __attribute__((ext_vector_type(16)));
typedef short  s16x8  __attribute__((ext_vector_type(8)));

#define DEV __device__ __forceinline__

static constexpr int    DHW       = 32768;       // 8*64*64
static constexpr int    NTOK      = 65536;       // B*D*H*W
static constexpr int    KCB       = 4096;        // codebook size
static constexpr int    CHUNK_B   = 18432;       // 16384 gh/gl + 1KB e2 + zero slot + pad
static constexpr size_t OUT_ELEMS = 4194304;     // 2*64*32768
static constexpr float  BIGC      = 512.0f;      // positivity bias for uint-compare
static constexpr float  TAU       = 0.015f;      // near-tie refinement threshold
static constexpr int    FLAG_CAP  = 8192;

// workspace byte offsets
static constexpr size_t WS_PREP = 0;                          // 64*18432 = 1,179,648
static constexpr size_t WS_RES  = 1179648;                    // 2*65536*8 = 1,048,576
static constexpr size_t WS_IDX  = 2228224;                    // 65536*4
static constexpr size_t WS_PART = 2490368;                    // 256*4
static constexpr size_t WS_CNT  = 2491392;                    // int
static constexpr size_t WS_FLAG = 2491648;                    // FLAG_CAP*4

DEV unsigned f2bf(float f) {            // RNE float -> bf16 bits
  unsigned u = __float_as_uint(f);
  return (u + 0x7FFFu + ((u >> 16) & 1u)) >> 16;
}
DEV float bf2f(unsigned h) { return __uint_as_float(h << 16); }
DEV unsigned med3u(unsigned a, unsigned b, unsigned c) {
  unsigned r;
  asm("v_med3_u32 %0, %1, %2, %3" : "=v"(r) : "v"(a), "v"(b), "v"(c));
  return r;
}
DEV void gl_lds16(const void* g, void* l) {   // 64 lanes x 16B, dest = base + lane*16
  __builtin_amdgcn_global_load_lds(
      (const __attribute__((address_space(1))) unsigned int*)g,
      (__attribute__((address_space(3))) unsigned int*)l, 16, 0, 0);
}

// ---------------- Kernel A: pre-conv (t = pre_w@z + pre_b) + embedding prep ----
// t stored [C=64][NTOK] inside d_out (overwritten later by k_post).
// prep chunk (64 codes): 64 rows x 256B [gh 128 | gl 128], byte o stored at o^((r&15)<<4)
// (pre-swizzled so staging is a linear copy); e2 triple-split at 16384 + r*16; zero slot at +1024.
__global__ __launch_bounds__(256) void k_pre(const float* __restrict__ z,
    const float* __restrict__ emb, const float* __restrict__ pw, const float* __restrict__ pb,
    float* __restrict__ dout, char* __restrict__ ws)
{
  const int blk = blockIdx.x, tid = threadIdx.x;
  if (blk == 0 && tid == 0) *(int*)(ws + WS_CNT) = 0;
  if (blk < 256) {
    float* t = dout;
    const int v = blk * 256 + tid;
    const int b = v >> 15, r = v & (DHW - 1);
    const float* zp = z + (size_t)b * 64 * DHW + r;
    float zr[64];
#pragma unroll
    for (int c2 = 0; c2 < 64; ++c2) zr[c2] = zp[(size_t)c2 * DHW];
    for (int c = 0; c < 64; ++c) {          // c uniform -> pre_w row via s_load
      float a = pb[c];
      const float* wr = pw + c * 64;
#pragma unroll
      for (int c2 = 0; c2 < 64; ++c2) a = fmaf(wr[c2], zr[c2], a);
      t[(size_t)c * NTOK + v] = a;          // coalesced across lanes
    }
  } else {
    const int tt = (blk - 256) * 256 + tid;  // 0..16383, 2 units each
#pragma unroll
    for (int uu = 0; uu < 2; ++uu) {
      const int u = tt * 2 + uu;
      const int k = u >> 3, j = u & 7;       // code k, 8-channel group j
      const float* ep = emb + (size_t)k * 64 + j * 8;
      unsigned hw[4], lw[4];
#pragma unroll
      for (int i = 0; i < 4; ++i) {
        float g0 = -2.0f * ep[2 * i], g1 = -2.0f * ep[2 * i + 1];
        unsigned h0 = f2bf(g0); unsigned l0 = f2bf(g0 - bf2f(h0));
        unsigned h1 = f2bf(g1); unsigned l1 = f2bf(g1 - bf2f(h1));
        hw[i] = h0 | (h1 << 16); lw[i] = l0 | (l1 << 16);
      }
      char* base = ws + WS_PREP + (size_t)(k >> 6) * CHUNK_B;
      const int r = k & 63;
      const int swz = (r & 15) << 4;
      char* rowp = base + r * 256;
      *(uint4*)(rowp + ((j * 16) ^ swz))        = make_uint4(hw[0], hw[1], hw[2], hw[3]);
      *(uint4*)(rowp + ((128 + j * 16) ^ swz))  = make_uint4(lw[0], lw[1], lw[2], lw[3]);
      if (j == 0) {
        const float* er = emb + (size_t)k * 64;
        float s = 0.f;
#pragma unroll
        for (int c = 0; c < 64; ++c) s = fmaf(er[c], er[c], s);
        s += BIGC;
        unsigned eh  = f2bf(s);
        float    rs  = s - bf2f(eh);
        unsigned el  = f2bf(rs);
        unsigned el2 = f2bf(rs - bf2f(el));
        *(uint4*)(base + 16384 + r * 16) = make_uint4(eh | (el << 16), el2, 0u, 0u);
        if (r == 0) *(uint4*)(base + 16384 + 1024) = make_uint4(0u, 0u, 0u, 0u);
      }
    }
  }
}

// ---------------- Kernel B: bf16x3 MFMA distance (32x32x16) + per-half argmin --
// 512 blocks x 512 thr. Block b: tokens (b>>1)*256..+256, chunks half (b&1)*32..+32.
// e2 (=512+||e||^2, triple bf16 split) folded in via one extra MFMA per rowtile.
__global__ __launch_bounds__(512, 4) void k_dist(float* __restrict__ dout,
                                                 char* __restrict__ ws)
{
  __shared__ __align__(16) char smem[2 * CHUNK_B];
  const float* t = dout;                       // [64][NTOK]
  const int tid = threadIdx.x;
  const int w = tid >> 6, lane = tid & 63;
  const int l31 = lane & 31, khalf = lane >> 5;
  const int gidx = blockIdx.x >> 1, h = blockIdx.x & 1;
  const int tb = gidx * 256 + w * 32;
  const int tok = tb + l31;

  // ---- B-fragments: t[k][tok], k = kt*16 + khalf*8 + i ----
  s16x8 tav[4], tlv[4];
#pragma unroll
  for (int kt = 0; kt < 4; ++kt) {
    const float* tc = t + (size_t)(kt * 16 + khalf * 8) * NTOK + tok;
    float f[8];
#pragma unroll
    for (int i = 0; i < 8; ++i) f[i] = tc[(size_t)i * NTOK];
    union { unsigned u[4]; s16x8 v; } xh, xl;
#pragma unroll
    for (int i = 0; i < 4; ++i) {
      unsigned h0 = f2bf(f[2 * i]),     l0 = f2bf(f[2 * i]     - bf2f(h0));
      unsigned h1 = f2bf(f[2 * i + 1]), l1 = f2bf(f[2 * i + 1] - bf2f(h1));
      xh.u[i] = h0 | (h1 << 16); xl.u[i] = l0 | (l1 << 16);
    }
    tav[kt] = xh.v; tlv[kt] = xl.v;
  }
  s16x8 ones;                                  // B for e2-MFMA: k'=0,1,2 -> 1.0 (khalf 0)
  { union { unsigned u[4]; s16x8 v; } o;
    o.u[0] = khalf ? 0u : 0x3F803F80u;
    o.u[1] = khalf ? 0u : 0x00003F80u;
    o.u[2] = 0u; o.u[3] = 0u; ones = o.v; }

  const char* prep = ws + WS_PREP + (size_t)h * 32 * CHUNK_B;
  const int swz = (l31 & 15) << 4;

  // prologue: stage chunk 0 (linear copy: prep is pre-swizzled)
  {
    const char* src = prep;
    gl_lds16(src + w * 1024 + lane * 16, smem + w * 1024);
    gl_lds16(src + 8192 + w * 1024 + lane * 16, smem + 8192 + w * 1024);
    if (w < 2) gl_lds16(src + 16384 + w * 1024 + lane * 16, smem + 16384 + w * 1024);
  }
  __syncthreads();

  unsigned u1 = 0x7f800000u, u2 = 0x7f800000u;
  int c1 = 0;

  for (int c = 0; c < 32; ++c) {
    const char* L = smem + (c & 1) * CHUNK_B;
    if (c + 1 < 32) {                          // issue next-chunk stage early
      const char* src = prep + (size_t)(c + 1) * CHUNK_B;
      char* dst = smem + ((c + 1) & 1) * CHUNK_B;
      gl_lds16(src + w * 1024 + lane * 16, dst + w * 1024);
      gl_lds16(src + 8192 + w * 1024 + lane * 16, dst + 8192 + w * 1024);
      if (w < 2) gl_lds16(src + 16384 + w * 1024 + lane * 16, dst + 16384 + w * 1024);
    }
    f32x16 acc0 = {}, acc1 = {};
    {                                          // e2 seed via MFMA (adds 512+||e||^2)
      const s16x8 e0 = *(const s16x8*)(L + (khalf ? (16384 + 1024) : (16384 + l31 * 16)));
      const s16x8 e1 = *(const s16x8*)(L + (khalf ? (16384 + 1024) : (16384 + (32 + l31) * 16)));
      acc0 = __builtin_amdgcn_mfma_f32_32x32x16_bf16(e0, ones, acc0, 0, 0, 0);
      acc1 = __builtin_amdgcn_mfma_f32_32x32x16_bf16(e1, ones, acc1, 0, 0, 0);
    }
#pragma unroll
    for (int kt = 0; kt < 4; ++kt) {
      const int i0 = (kt * 32 + khalf * 16) ^ swz;
      const s16x8 gh0 = *(const s16x8*)(L + l31 * 256 + i0);
      const s16x8 gl0 = *(const s16x8*)(L + l31 * 256 + (i0 ^ 128));
      const s16x8 gh1 = *(const s16x8*)(L + (32 + l31) * 256 + i0);
      const s16x8 gl1 = *(const s16x8*)(L + (32 + l31) * 256 + (i0 ^ 128));
      acc0 = __builtin_amdgcn_mfma_f32_32x32x16_bf16(gh0, tav[kt], acc0, 0, 0, 0);
      acc0 = __builtin_amdgcn_mfma_f32_32x32x16_bf16(gh0, tlv[kt], acc0, 0, 0, 0);
      acc0 = __builtin_amdgcn_mfma_f32_32x32x16_bf16(gl0, tav[kt], acc0, 0, 0, 0);
      acc1 = __builtin_amdgcn_mfma_f32_32x32x16_bf16(gh1, tav[kt], acc1, 0, 0, 0);
      acc1 = __builtin_amdgcn_mfma_f32_32x32x16_bf16(gh1, tlv[kt], acc1, 0, 0, 0);
      acc1 = __builtin_amdgcn_mfma_f32_32x32x16_bf16(gl1, tav[kt], acc1, 0, 0, 0);
    }
    // argmin: C row = rt*32 + (q&3) + 8*(q>>2) + 4*khalf; embed widc (rbase |'d at end)
    const unsigned p1 = u1;
#pragma unroll
    for (int q = 0; q < 16; ++q) {
      const unsigned w0 = (unsigned)((q & 3) + 8 * (q >> 2));
      unsigned v0 = (__float_as_uint(acc0[q]) & ~63u) | w0;
      u2 = med3u(u1, v0, u2); u1 = u1 < v0 ? u1 : v0;
      unsigned v1 = (__float_as_uint(acc1[q]) & ~63u) | (w0 + 32u);
      u2 = med3u(u1, v1, u2); u1 = u1 < v1 ? u1 : v1;
    }
    if (u1 != p1) c1 = c;
    __syncthreads();                           // drains vmcnt -> next chunk staged
  }

  u1 |= (unsigned)(khalf * 4);                 // complete wid (bit 2)
  // merge lane <-> lane+32 (same token, different code rows)
  const unsigned o1 = __shfl_xor(u1, 32);
  const unsigned o2 = __shfl_xor(u2, 32);
  const int      oc = __shfl_xor(c1, 32);
  const unsigned am = u1 & ~63u, om = o1 & ~63u;
  const int mycode = c1 * 64 + (int)(u1 & 63u);
  const int ocode  = oc * 64 + (int)(o1 & 63u);
  const bool owins = (om < am) || (om == am && ocode < mycode);
  const unsigned f1 = owins ? o1 : u1;
  const int      fc = owins ? oc : c1;
  const unsigned mx = owins ? am : om;
  unsigned s2 = (u2 & ~63u) < (o2 & ~63u) ? (u2 & ~63u) : (o2 & ~63u);
  s2 = s2 < mx ? s2 : mx;
  if (khalf == 0) {
    uint2* res = (uint2*)(ws + WS_RES);
    res[h * 65536 + tok] = make_uint2(f1, s2 | (unsigned)fc);
  }
}

// ---------------- Kernel M: merge halves -> idx/fidx/flags + loss partials -----
__global__ __launch_bounds__(256) void k_merge(const float* __restrict__ emb,
    float* __restrict__ dout, char* __restrict__ ws)
{
  __shared__ float ls[4];
  const int v = blockIdx.x * 256 + threadIdx.x;
  const uint2* res = (const uint2*)(ws + WS_RES);
  const uint2 A = res[v], B = res[65536 + v];
  const unsigned am = A.x & ~63u, bm = B.x & ~63u;
  const int codeA = (int)(A.y & 63u) * 64 + (int)(A.x & 63u);
  const int codeB = 2048 + (int)(B.y & 63u) * 64 + (int)(B.x & 63u);
  const bool bwins = bm < am;                  // tie -> A (always lower code)
  const int code = bwins ? codeB : codeA;
  const unsigned fb = bwins ? bm : am;
  const unsigned mx = bwins ? am : bm;
  unsigned f2 = (A.y & ~63u) < (B.y & ~63u) ? (A.y & ~63u) : (B.y & ~63u);
  f2 = f2 < mx ? f2 : mx;
  ((int*)(ws + WS_IDX))[v] = code;
  dout[OUT_ELEMS + 2 + v] = (float)code;
  if (__uint_as_float(f2) - __uint_as_float(fb) < TAU) {
    int p = atomicAdd((int*)(ws + WS_CNT), 1);
    if (p < FLAG_CAP) ((int*)(ws + WS_FLAG))[p] = v;
  }
  // loss: sum (t - q)^2 for this token
  const float* tcol = dout + v;                // t[c][v]
  const float* q = emb + (size_t)code * 64;
  float acc = 0.f;
#pragma unroll
  for (int cch = 0; cch < 64; ++cch) {
    const float d = tcol[(size_t)cch * NTOK] - q[cch];
    acc = fmaf(d, d, acc);
  }
#pragma unroll
  for (int m = 1; m < 64; m <<= 1) acc += __shfl_xor(acc, m);
  const int lane = threadIdx.x & 63, wv = threadIdx.x >> 6;
  if (lane == 0) ls[wv] = acc;
  __syncthreads();
  if (threadIdx.x == 0)
    ((float*)(ws + WS_PART))[blockIdx.x] = ls[0] + ls[1] + ls[2] + ls[3];
}

// ---------------- Kernel R: f64 re-scan of near-tie tokens (8 per block) -------
__global__ __launch_bounds__(256) void k_refine(const float* __restrict__ z,
    const float* __restrict__ emb, const float* __restrict__ pw, const float* __restrict__ pb,
    float* __restrict__ dout, char* __restrict__ ws)
{
  int cv = *(const int*)(ws + WS_CNT);
  if (cv > FLAG_CAP) cv = FLAG_CAP;
  const int base = blockIdx.x * 8;
  if (base >= cv) return;
  const int nt = (cv - base < 8) ? (cv - base) : 8;
  const int tid = threadIdx.x;
  __shared__ double td[8][64];
  __shared__ int tks[8];
  __shared__ double dsw[4]; __shared__ int ksw[4];
  if (tid < nt) tks[tid] = ((const int*)(ws + WS_FLAG))[base + tid];
  __syncthreads();
  for (int u = tid; u < nt * 64; u += 256) {   // FIX: nt*64 can exceed 256 threads
    const int s = u >> 6, ch = u & 63;
    const int n = tks[s];
    const int b = n >> 15, r = n & (DHW - 1);
    const float* zp = z + (size_t)b * 64 * DHW + r;
    const float* wr = pw + ch * 64;
    double a = (double)pb[ch];
    for (int c2 = 0; c2 < 64; ++c2) a += (double)wr[c2] * (double)zp[(size_t)c2 * DHW];
    td[s][ch] = a;
  }
  __syncthreads();
  double dmin[8]; int kmin[8];
#pragma unroll
  for (int s = 0; s < 8; ++s) { dmin[s] = 1e300; kmin[s] = 0; }
  for (int k0 = 0; k0 < KCB; k0 += 256) {
    const int k = k0 + tid;
    const float* e = emb + (size_t)k * 64;
    float er[64];
#pragma unroll
    for (int i = 0; i < 16; ++i) *(float4*)(er + i * 4) = *(const float4*)(e + i * 4);
#pragma unroll
    for (int s = 0; s < 8; ++s) {
      if (s < nt) {
        double d0 = 0.0, d1 = 0.0;
#pragma unroll
        for (int ch = 0; ch < 64; ch += 2) {
          const double x0 = td[s][ch]     - (double)er[ch];
          const double x1 = td[s][ch + 1] - (double)er[ch + 1];
          d0 = fma(x0, x0, d0); d1 = fma(x1, x1, d1);
        }
        const double d = d0 + d1;
        if (d < dmin[s]) { dmin[s] = d; kmin[s] = k; }  // ascending k: first wins
      }
    }
  }
  const int lane = tid & 63, wv = tid >> 6;
#pragma unroll
  for (int s = 0; s < 8; ++s) {
    if (s >= nt) break;
    double dm = dmin[s]; int km = kmin[s];
#pragma unroll
    for (int m = 1; m < 64; m <<= 1) {
      const double od = __shfl_xor(dm, m); const int ok = __shfl_xor(km, m);
      if (od < dm || (od == dm && ok < km)) { dm = od; km = ok; }
    }
    if (lane == 0) { dsw[wv] = dm; ksw[wv] = km; }
    __syncthreads();
    if (tid == 0) {
      for (int i = 1; i < 4; ++i)
        if (dsw[i] < dm || (dsw[i] == dm && ksw[i] < km)) { dm = dsw[i]; km = ksw[i]; }
      const int n = tks[s];
      ((int*)(ws + WS_IDX))[n] = km;
      dout[OUT_ELEMS + 2 + n] = (float)km;
    }
    __syncthreads();
  }
}

// ---------------- Kernel D: post-conv (out = post_w@q + post_b) + loss final ---
__global__ __launch_bounds__(256) void k_post(const float* __restrict__ emb,
    const float* __restrict__ ow, const float* __restrict__ ob,
    float* __restrict__ dout, const char* __restrict__ ws)
{
  __shared__ float ps[256];
  const int v = blockIdx.x * 256 + threadIdx.x;
  const int b = v >> 15, r = v & (DHW - 1);
  const int code = ((const int*)(ws + WS_IDX))[v];
  const float* q = emb + (size_t)code * 64;
  float qr[64];
#pragma unroll
  for (int i = 0; i < 64; ++i) qr[i] = q[i];
  float* op = dout + (size_t)b * 64 * DHW + r;
  for (int o = 0; o < 64; ++o) {              // o uniform -> post_w row via s_load
    float a = ob[o];
    const float* wr = ow + o * 64;
#pragma unroll
    for (int cch = 0; cch < 64; ++cch) a = fmaf(wr[cch], qr[cch], a);
    op[(size_t)o * DHW] = a;                  // coalesced
  }
  if (blockIdx.x == 0) {
    ps[threadIdx.x] = ((const float*)(ws + WS_PART))[threadIdx.x];
    __syncthreads();
    if (threadIdx.x == 0) {
      float s = 0.f;
      for (int i = 0; i < 256; ++i) s += ps[i];   // fixed order: deterministic
      const float mean = s / 4194304.0f;
      dout[OUT_ELEMS]     = mean;   // codebook_loss
      dout[OUT_ELEMS + 1] = mean;   // commitment_loss
    }
  }
}

extern "C" void kernel_launch(void* const* d_in, const int* in_sizes, int n_in,
                              void* d_out, int out_size, void* d_ws, size_t ws_size,
                              hipStream_t stream) {
  (void)in_sizes; (void)n_in; (void)out_size; (void)ws_size;
  const float* z   = (const float*)d_in[0];
  const float* emb = (const float*)d_in[1];
  const float* pw  = (const float*)d_in[2];
  const float* pb  = (const float*)d_in[3];
  const float* ow  = (const float*)d_in[4];
  const float* ob  = (const float*)d_in[5];
  float* out = (float*)d_out;
  char*  ws  = (char*)d_ws;

  hipLaunchKernelGGL(k_pre,    dim3(320),  dim3(256), 0, stream, z, emb, pw, pb, out, ws);
  hipLaunchKernelGGL(k_dist,   dim3(512),  dim3(512), 0, stream, out, ws);
  hipLaunchKernelGGL(k_merge,  dim3(256),  dim3(256), 0, stream, emb, out, ws);
  hipLaunchKernelGGL(k_refine, dim3(FLAG_CAP / 8), dim3(256), 0, stream, z, emb, pw, pb, out, ws);
  hipLaunchKernelGGL(k_post,   dim3(256),  dim3(256), 0, stream, emb, ow, ob, out, ws);
}

// Round 4
// 270.032 us; speedup vs baseline: 2.3844x; 2.3844x over previous
//
#include <hip/hip_runtime.h>
#include <cstdint>
#include <cstddef>

typedef float  f32x4  __attribute__((ext_vector_type(4)));
typedef float  f32x16 __attribute__((ext_vector_type(16)));
typedef short  s16x8  __attribute__((ext_vector_type(8)));

#define DEV __device__ __forceinline__

static constexpr int    DHW       = 32768;       // 8*64*64
static constexpr int    NTOK      = 65536;       // B*D*H*W
static constexpr int    KCB       = 4096;        // codebook size
static constexpr int    CHUNK_B   = 18432;       // 16384 gh/gl + 1KB e2 + zero slot + pad
static constexpr size_t OUT_ELEMS = 4194304;     // 2*64*32768
static constexpr float  BIGC      = 512.0f;      // positivity bias for uint-compare
static constexpr float  TAU       = 0.015f;      // near-tie refinement threshold
static constexpr int    FLAG_CAP  = 8192;

// workspace byte offsets
static constexpr size_t WS_PREP = 0;                          // 64*18432 = 1,179,648
static constexpr size_t WS_RES  = 1179648;                    // 2*65536*8 = 1,048,576
static constexpr size_t WS_IDX  = 2228224;                    // 65536*4
static constexpr size_t WS_PART = 2490368;                    // 256*4
static constexpr size_t WS_CNT  = 2491392;                    // int
static constexpr size_t WS_FLAG = 2491648;                    // FLAG_CAP*4

DEV unsigned f2bf(float f) {            // RNE float -> bf16 bits
  unsigned u = __float_as_uint(f);
  return (u + 0x7FFFu + ((u >> 16) & 1u)) >> 16;
}
DEV float bf2f(unsigned h) { return __uint_as_float(h << 16); }
DEV unsigned med3u(unsigned a, unsigned b, unsigned c) {
  unsigned r;
  asm("v_med3_u32 %0, %1, %2, %3" : "=v"(r) : "v"(a), "v"(b), "v"(c));
  return r;
}
DEV void gl_lds16(const void* g, void* l) {   // 64 lanes x 16B, dest = base + lane*16
  __builtin_amdgcn_global_load_lds(
      (const __attribute__((address_space(1))) unsigned int*)g,
      (__attribute__((address_space(3))) unsigned int*)l, 16, 0, 0);
}

// ---------------- Kernel A: pre-conv (t = pre_w@z + pre_b) + embedding prep ----
// t stored [C=64][NTOK] inside d_out (overwritten later by k_post).
// prep chunk (64 codes): 64 rows x 256B [gh 128 | gl 128], byte o stored at o^((r&15)<<4)
// (pre-swizzled so staging is a linear copy); e2 triple-split at 16384 + r*16; zero slot at +1024.
__global__ __launch_bounds__(256) void k_pre(const float* __restrict__ z,
    const float* __restrict__ emb, const float* __restrict__ pw, const float* __restrict__ pb,
    float* __restrict__ dout, char* __restrict__ ws)
{
  const int blk = blockIdx.x, tid = threadIdx.x;
  if (blk == 0 && tid == 0) *(int*)(ws + WS_CNT) = 0;
  if (blk < 256) {
    float* t = dout;
    const int v = blk * 256 + tid;
    const int b = v >> 15, r = v & (DHW - 1);
    const float* zp = z + (size_t)b * 64 * DHW + r;
    float zr[64];
#pragma unroll
    for (int c2 = 0; c2 < 64; ++c2) zr[c2] = zp[(size_t)c2 * DHW];
    for (int c = 0; c < 64; ++c) {          // c uniform -> pre_w row via s_load
      float a = pb[c];
      const float* wr = pw + c * 64;
#pragma unroll
      for (int c2 = 0; c2 < 64; ++c2) a = fmaf(wr[c2], zr[c2], a);
      t[(size_t)c * NTOK + v] = a;          // coalesced across lanes
    }
  } else {
    const int tt = (blk - 256) * 256 + tid;  // 0..16383, 2 units each
#pragma unroll
    for (int uu = 0; uu < 2; ++uu) {
      const int u = tt * 2 + uu;
      const int k = u >> 3, j = u & 7;       // code k, 8-channel group j
      const float* ep = emb + (size_t)k * 64 + j * 8;
      unsigned hw[4], lw[4];
#pragma unroll
      for (int i = 0; i < 4; ++i) {
        float g0 = -2.0f * ep[2 * i], g1 = -2.0f * ep[2 * i + 1];
        unsigned h0 = f2bf(g0); unsigned l0 = f2bf(g0 - bf2f(h0));
        unsigned h1 = f2bf(g1); unsigned l1 = f2bf(g1 - bf2f(h1));
        hw[i] = h0 | (h1 << 16); lw[i] = l0 | (l1 << 16);
      }
      char* base = ws + WS_PREP + (size_t)(k >> 6) * CHUNK_B;
      const int r = k & 63;
      const int swz = (r & 15) << 4;
      char* rowp = base + r * 256;
      *(uint4*)(rowp + ((j * 16) ^ swz))        = make_uint4(hw[0], hw[1], hw[2], hw[3]);
      *(uint4*)(rowp + ((128 + j * 16) ^ swz))  = make_uint4(lw[0], lw[1], lw[2], lw[3]);
      if (j == 0) {
        const float* er = emb + (size_t)k * 64;
        float s = 0.f;
#pragma unroll
        for (int c = 0; c < 64; ++c) s = fmaf(er[c], er[c], s);
        s += BIGC;
        unsigned eh  = f2bf(s);
        float    rs  = s - bf2f(eh);
        unsigned el  = f2bf(rs);
        unsigned el2 = f2bf(rs - bf2f(el));
        *(uint4*)(base + 16384 + r * 16) = make_uint4(eh | (el << 16), el2, 0u, 0u);
        if (r == 0) *(uint4*)(base + 16384 + 1024) = make_uint4(0u, 0u, 0u, 0u);
      }
    }
  }
}

// ---------------- Kernel B: bf16x3 MFMA distance (32x32x16) + per-half argmin --
// 512 blocks x 512 thr. Block b: tokens (b>>1)*256..+256, chunks half (b&1)*32..+32.
// e2 (=512+||e||^2, triple bf16 split) folded in via one extra MFMA per rowtile.
__global__ __launch_bounds__(512, 4) void k_dist(float* __restrict__ dout,
                                                 char* __restrict__ ws)
{
  __shared__ __align__(16) char smem[2 * CHUNK_B];
  const float* t = dout;                       // [64][NTOK]
  const int tid = threadIdx.x;
  const int w = tid >> 6, lane = tid & 63;
  const int l31 = lane & 31, khalf = lane >> 5;
  const int gidx = blockIdx.x >> 1, h = blockIdx.x & 1;
  const int tb = gidx * 256 + w * 32;
  const int tok = tb + l31;

  // ---- B-fragments: t[k][tok], k = kt*16 + khalf*8 + i ----
  s16x8 tav[4], tlv[4];
#pragma unroll
  for (int kt = 0; kt < 4; ++kt) {
    const float* tc = t + (size_t)(kt * 16 + khalf * 8) * NTOK + tok;
    float f[8];
#pragma unroll
    for (int i = 0; i < 8; ++i) f[i] = tc[(size_t)i * NTOK];
    union { unsigned u[4]; s16x8 v; } xh, xl;
#pragma unroll
    for (int i = 0; i < 4; ++i) {
      unsigned h0 = f2bf(f[2 * i]),     l0 = f2bf(f[2 * i]     - bf2f(h0));
      unsigned h1 = f2bf(f[2 * i + 1]), l1 = f2bf(f[2 * i + 1] - bf2f(h1));
      xh.u[i] = h0 | (h1 << 16); xl.u[i] = l0 | (l1 << 16);
    }
    tav[kt] = xh.v; tlv[kt] = xl.v;
  }
  s16x8 ones;                                  // B for e2-MFMA: k'=0,1,2 -> 1.0 (khalf 0)
  { union { unsigned u[4]; s16x8 v; } o;
    o.u[0] = khalf ? 0u : 0x3F803F80u;
    o.u[1] = khalf ? 0u : 0x00003F80u;
    o.u[2] = 0u; o.u[3] = 0u; ones = o.v; }

  const char* prep = ws + WS_PREP + (size_t)h * 32 * CHUNK_B;
  const int swz = (l31 & 15) << 4;

  // prologue: stage chunk 0 (linear copy: prep is pre-swizzled)
  {
    const char* src = prep;
    gl_lds16(src + w * 1024 + lane * 16, smem + w * 1024);
    gl_lds16(src + 8192 + w * 1024 + lane * 16, smem + 8192 + w * 1024);
    if (w < 2) gl_lds16(src + 16384 + w * 1024 + lane * 16, smem + 16384 + w * 1024);
  }
  __syncthreads();

  unsigned u1 = 0x7f800000u, u2 = 0x7f800000u;
  int c1 = 0;

  for (int c = 0; c < 32; ++c) {
    const char* L = smem + (c & 1) * CHUNK_B;
    if (c + 1 < 32) {                          // issue next-chunk stage early
      const char* src = prep + (size_t)(c + 1) * CHUNK_B;
      char* dst = smem + ((c + 1) & 1) * CHUNK_B;
      gl_lds16(src + w * 1024 + lane * 16, dst + w * 1024);
      gl_lds16(src + 8192 + w * 1024 + lane * 16, dst + 8192 + w * 1024);
      if (w < 2) gl_lds16(src + 16384 + w * 1024 + lane * 16, dst + 16384 + w * 1024);
    }
    f32x16 acc0 = {}, acc1 = {};
    {                                          // e2 seed via MFMA (adds 512+||e||^2)
      const s16x8 e0 = *(const s16x8*)(L + (khalf ? (16384 + 1024) : (16384 + l31 * 16)));
      const s16x8 e1 = *(const s16x8*)(L + (khalf ? (16384 + 1024) : (16384 + (32 + l31) * 16)));
      acc0 = __builtin_amdgcn_mfma_f32_32x32x16_bf16(e0, ones, acc0, 0, 0, 0);
      acc1 = __builtin_amdgcn_mfma_f32_32x32x16_bf16(e1, ones, acc1, 0, 0, 0);
    }
#pragma unroll
    for (int kt = 0; kt < 4; ++kt) {
      const int i0 = (kt * 32 + khalf * 16) ^ swz;
      const s16x8 gh0 = *(const s16x8*)(L + l31 * 256 + i0);
      const s16x8 gl0 = *(const s16x8*)(L + l31 * 256 + (i0 ^ 128));
      const s16x8 gh1 = *(const s16x8*)(L + (32 + l31) * 256 + i0);
      const s16x8 gl1 = *(const s16x8*)(L + (32 + l31) * 256 + (i0 ^ 128));
      acc0 = __builtin_amdgcn_mfma_f32_32x32x16_bf16(gh0, tav[kt], acc0, 0, 0, 0);
      acc0 = __builtin_amdgcn_mfma_f32_32x32x16_bf16(gh0, tlv[kt], acc0, 0, 0, 0);
      acc0 = __builtin_amdgcn_mfma_f32_32x32x16_bf16(gl0, tav[kt], acc0, 0, 0, 0);
      acc1 = __builtin_amdgcn_mfma_f32_32x32x16_bf16(gh1, tav[kt], acc1, 0, 0, 0);
      acc1 = __builtin_amdgcn_mfma_f32_32x32x16_bf16(gh1, tlv[kt], acc1, 0, 0, 0);
      acc1 = __builtin_amdgcn_mfma_f32_32x32x16_bf16(gl1, tav[kt], acc1, 0, 0, 0);
    }
    // argmin: C row = rt*32 + (q&3) + 8*(q>>2) + 4*khalf; embed widc (rbase |'d at end)
    const unsigned p1 = u1;
#pragma unroll
    for (int q = 0; q < 16; ++q) {
      const unsigned w0 = (unsigned)((q & 3) + 8 * (q >> 2));
      unsigned v0 = (__float_as_uint(acc0[q]) & ~63u) | w0;
      u2 = med3u(u1, v0, u2); u1 = u1 < v0 ? u1 : v0;
      unsigned v1 = (__float_as_uint(acc1[q]) & ~63u) | (w0 + 32u);
      u2 = med3u(u1, v1, u2); u1 = u1 < v1 ? u1 : v1;
    }
    if (u1 != p1) c1 = c;
    __syncthreads();                           // drains vmcnt -> next chunk staged
  }

  u1 |= (unsigned)(khalf * 4);                 // complete wid (bit 2)
  // merge lane <-> lane+32 (same token, different code rows)
  const unsigned o1 = __shfl_xor(u1, 32);
  const unsigned o2 = __shfl_xor(u2, 32);
  const int      oc = __shfl_xor(c1, 32);
  const unsigned am = u1 & ~63u, om = o1 & ~63u;
  const int mycode = c1 * 64 + (int)(u1 & 63u);
  const int ocode  = oc * 64 + (int)(o1 & 63u);
  const bool owins = (om < am) || (om == am && ocode < mycode);
  const unsigned f1 = owins ? o1 : u1;
  const int      fc = owins ? oc : c1;
  const unsigned mx = owins ? am : om;
  unsigned s2 = (u2 & ~63u) < (o2 & ~63u) ? (u2 & ~63u) : (o2 & ~63u);
  s2 = s2 < mx ? s2 : mx;
  if (khalf == 0) {
    uint2* res = (uint2*)(ws + WS_RES);
    res[h * 65536 + tok] = make_uint2(f1, s2 | (unsigned)fc);
  }
}

// ---------------- Kernel M: merge halves -> idx/fidx/flags + loss partials -----
__global__ __launch_bounds__(256) void k_merge(const float* __restrict__ emb,
    float* __restrict__ dout, char* __restrict__ ws)
{
  __shared__ float ls[4];
  const int v = blockIdx.x * 256 + threadIdx.x;
  const uint2* res = (const uint2*)(ws + WS_RES);
  const uint2 A = res[v], B = res[65536 + v];
  const unsigned am = A.x & ~63u, bm = B.x & ~63u;
  const int codeA = (int)(A.y & 63u) * 64 + (int)(A.x & 63u);
  const int codeB = 2048 + (int)(B.y & 63u) * 64 + (int)(B.x & 63u);
  const bool bwins = bm < am;                  // tie -> A (always lower code)
  const int code = bwins ? codeB : codeA;
  const unsigned fb = bwins ? bm : am;
  const unsigned mx = bwins ? am : bm;
  unsigned f2 = (A.y & ~63u) < (B.y & ~63u) ? (A.y & ~63u) : (B.y & ~63u);
  f2 = f2 < mx ? f2 : mx;
  ((int*)(ws + WS_IDX))[v] = code;
  dout[OUT_ELEMS + 2 + v] = (float)code;
  if (__uint_as_float(f2) - __uint_as_float(fb) < TAU) {
    int p = atomicAdd((int*)(ws + WS_CNT), 1);
    if (p < FLAG_CAP) ((int*)(ws + WS_FLAG))[p] = v;
  }
  // loss: sum (t - q)^2 for this token
  const float* tcol = dout + v;                // t[c][v]
  const float* q = emb + (size_t)code * 64;
  float acc = 0.f;
#pragma unroll
  for (int cch = 0; cch < 64; ++cch) {
    const float d = tcol[(size_t)cch * NTOK] - q[cch];
    acc = fmaf(d, d, acc);
  }
#pragma unroll
  for (int m = 1; m < 64; m <<= 1) acc += __shfl_xor(acc, m);
  const int lane = threadIdx.x & 63, wv = threadIdx.x >> 6;
  if (lane == 0) ls[wv] = acc;
  __syncthreads();
  if (threadIdx.x == 0)
    ((float*)(ws + WS_PART))[blockIdx.x] = ls[0] + ls[1] + ls[2] + ls[3];
}

// ---------------- Kernel R: f64 re-scan of near-tie tokens --------------------
// Wave-per-token (4/block). Codebook staged in double-buffered XOR-swizzled LDS
// tiles (64 codes x 256B) shared by all 4 waves. Scalar dmin/kmin only (no
// runtime-indexed arrays -> no scratch spill, the round-3 killer).
__global__ __launch_bounds__(256) void k_refine(const float* __restrict__ z,
    const float* __restrict__ emb, const float* __restrict__ pw, const float* __restrict__ pb,
    float* __restrict__ dout, char* __restrict__ ws)
{
  __shared__ __align__(16) float etile[2][4096];   // 2 x 16KB swizzled code tiles
  __shared__ double tdsh[4][64];                   // per-wave token t (f64)
  int cv = *(const int*)(ws + WS_CNT);
  if (cv > FLAG_CAP) cv = FLAG_CAP;
  const int base = blockIdx.x * 4;
  if (base >= cv) return;
  const int tid = threadIdx.x;
  const int w = tid >> 6, lane = tid & 63;
  const int slot = base + w;
  const bool active = slot < cv;
  const int n = active ? ((const int*)(ws + WS_FLAG))[slot] : 0;

  // recompute this token's t in f64 (lane l -> channel l), like round-1 (proven)
  if (active) {
    const int b = n >> 15, r = n & (DHW - 1);
    const float* zp = z + (size_t)b * 64 * DHW + r;
    const float* wr = pw + lane * 64;
    double a = (double)pb[lane];
    for (int c2 = 0; c2 < 64; ++c2)
      a = fma((double)wr[c2], (double)zp[(size_t)c2 * DHW], a);
    tdsh[w][lane] = a;
  }
  __syncthreads();
  const int s = lane >> 4, lo = lane & 15;
  double tdv[16];                                  // channels s*16 .. s*16+15
#pragma unroll
  for (int j = 0; j < 16; ++j) tdv[j] = tdsh[w][s * 16 + j];

  // stage tile 0: unit u = tid + 256k -> code c=u>>4, granule g=u&15,
  // swizzled byte = c*256 + ((g*16) ^ ((c&15)<<4))  (conflict-free both sides)
  const float4* esrc = (const float4*)emb;
  float4 rg0, rg1, rg2, rg3;
  rg0 = esrc[tid]; rg1 = esrc[tid + 256]; rg2 = esrc[tid + 512]; rg3 = esrc[tid + 768];
  {
    char* bp = (char*)etile[0];
#pragma unroll
    for (int k = 0; k < 4; ++k) {
      const int u = tid + 256 * k, c = u >> 4, g = u & 15;
      const float4 rv = k == 0 ? rg0 : k == 1 ? rg1 : k == 2 ? rg2 : rg3;
      *(float4*)(bp + c * 256 + ((g * 16) ^ ((c & 15) << 4))) = rv;
    }
  }
  __syncthreads();

  const int ebase0 = lo * 256 + ((s << 6) ^ (lo << 4));
  double dmin = 1e300; int kmin = 0;

  for (int t = 0; t < 64; ++t) {
    if (t < 63) {                                  // issue next-tile loads early
      const float4* src = esrc + (t + 1) * 1024;
      rg0 = src[tid]; rg1 = src[tid + 256]; rg2 = src[tid + 512]; rg3 = src[tid + 768];
    }
    if (active) {
      const char* buf = (const char*)etile[t & 1];
#pragma unroll
      for (int p = 0; p < 4; ++p) {
        const char* bp = buf + p * 4096;
        const float4 e0 = *(const float4*)(bp + (ebase0 ^ 0));
        const float4 e1 = *(const float4*)(bp + (ebase0 ^ 16));
        const float4 e2 = *(const float4*)(bp + (ebase0 ^ 32));
        const float4 e3 = *(const float4*)(bp + (ebase0 ^ 48));
        double d0 = 0.0, d1 = 0.0;
#define ACC4(E, J) { \
        const double x0 = tdv[J]     - (double)E.x; d0 = fma(x0, x0, d0); \
        const double x1 = tdv[J + 1] - (double)E.y; d1 = fma(x1, x1, d1); \
        const double x2 = tdv[J + 2] - (double)E.z; d0 = fma(x2, x2, d0); \
        const double x3 = tdv[J + 3] - (double)E.w; d1 = fma(x3, x3, d1); }
        ACC4(e0, 0) ACC4(e1, 4) ACC4(e2, 8) ACC4(e3, 12)
#undef ACC4
        double dsum = d0 + d1;
        dsum += __shfl_xor(dsum, 16);              // IEEE add commutative -> quad-identical
        dsum += __shfl_xor(dsum, 32);
        const int code = t * 64 + p * 16 + lo;     // ascending -> strict < keeps first
        if (dsum < dmin) { dmin = dsum; kmin = code; }
      }
    }
    __syncthreads();                               // readers done with buf[(t+1)&1]
    if (t < 63) {
      char* bp = (char*)etile[(t + 1) & 1];
#pragma unroll
      for (int k = 0; k < 4; ++k) {
        const int u = tid + 256 * k, c = u >> 4, g = u & 15;
        const float4 rv = k == 0 ? rg0 : k == 1 ? rg1 : k == 2 ? rg2 : rg3;
        *(float4*)(bp + c * 256 + ((g * 16) ^ ((c & 15) << 4))) = rv;
      }
    }
    __syncthreads();                               // writes visible for next tile
  }

  // merge the 16 per-lane code classes (s-groups are redundant duplicates)
#pragma unroll
  for (int m = 1; m < 16; m <<= 1) {
    const double od = __shfl_xor(dmin, m);
    const int    ok = __shfl_xor(kmin, m);
    if (od < dmin || (od == dmin && ok < kmin)) { dmin = od; kmin = ok; }
  }
  if (active && lane == 0) {
    ((int*)(ws + WS_IDX))[n] = kmin;
    dout[OUT_ELEMS + 2 + n] = (float)kmin;
  }
}

// ---------------- Kernel D: post-conv (out = post_w@q + post_b) + loss final ---
__global__ __launch_bounds__(256) void k_post(const float* __restrict__ emb,
    const float* __restrict__ ow, const float* __restrict__ ob,
    float* __restrict__ dout, const char* __restrict__ ws)
{
  __shared__ float ps[256];
  const int v = blockIdx.x * 256 + threadIdx.x;
  const int b = v >> 15, r = v & (DHW - 1);
  const int code = ((const int*)(ws + WS_IDX))[v];
  const float* q = emb + (size_t)code * 64;
  float qr[64];
#pragma unroll
  for (int i = 0; i < 64; ++i) qr[i] = q[i];
  float* op = dout + (size_t)b * 64 * DHW + r;
  for (int o = 0; o < 64; ++o) {              // o uniform -> post_w row via s_load
    float a = ob[o];
    const float* wr = ow + o * 64;
#pragma unroll
    for (int cch = 0; cch < 64; ++cch) a = fmaf(wr[cch], qr[cch], a);
    op[(size_t)o * DHW] = a;                  // coalesced
  }
  if (blockIdx.x == 0) {
    ps[threadIdx.x] = ((const float*)(ws + WS_PART))[threadIdx.x];
    __syncthreads();
    if (threadIdx.x == 0) {
      float s = 0.f;
      for (int i = 0; i < 256; ++i) s += ps[i];   // fixed order: deterministic
      const float mean = s / 4194304.0f;
      dout[OUT_ELEMS]     = mean;   // codebook_loss
      dout[OUT_ELEMS + 1] = mean;   // commitment_loss
    }
  }
}

extern "C" void kernel_launch(void* const* d_in, const int* in_sizes, int n_in,
                              void* d_out, int out_size, void* d_ws, size_t ws_size,
                              hipStream_t stream) {
  (void)in_sizes; (void)n_in; (void)out_size; (void)ws_size;
  const float* z   = (const float*)d_in[0];
  const float* emb = (const float*)d_in[1];
  const float* pw  = (const float*)d_in[2];
  const float* pb  = (const float*)d_in[3];
  const float* ow  = (const float*)d_in[4];
  const float* ob  = (const float*)d_in[5];
  float* out = (float*)d_out;
  char*  ws  = (char*)d_ws;

  hipLaunchKernelGGL(k_pre,    dim3(320),  dim3(256), 0, stream, z, emb, pw, pb, out, ws);
  hipLaunchKernelGGL(k_dist,   dim3(512),  dim3(512), 0, stream, out, ws);
  hipLaunchKernelGGL(k_merge,  dim3(256),  dim3(256), 0, stream, emb, out, ws);
  hipLaunchKernelGGL(k_refine, dim3(FLAG_CAP / 4), dim3(256), 0, stream, z, emb, pw, pb, out, ws);
  hipLaunchKernelGGL(k_post,   dim3(256),  dim3(256), 0, stream, emb, ow, ob, out, ws);
}